// Round 3
// baseline (190.126 us; speedup 1.0000x reference)
//
#include <hip/hip_runtime.h>

// MultiHotEmbedding: out[b,s,d] = (1/max(sum_n x[b,s,n],1)) * sum_n x[b,s,n]*emb[n,d]
// B=16, S=200, N=10000, D=64. x is float32 (0/1 multi-hot, ~50 active/row).
//
// Strategy: 1 block (256 thr = 4 waves) per row. Stream the 10000-float row as
// float4 (coalesced), ballot-scan for nonzeros, per active class do one
// wave-coalesced 256B emb read (L2-resident table), FMA into per-lane dim acc.
// Cross-wave reduce via LDS; wave 0 scales by 1/max(rowsum,1) and writes 64 floats.

#define NCLS 10000
#define DIM 64
#define NROWS (16 * 200)

__global__ __launch_bounds__(256) void multihot_emb_kernel(
    const float* __restrict__ x,
    const float* __restrict__ emb,
    float* __restrict__ out) {

    const int row  = blockIdx.x;        // 0..3199
    const int t    = threadIdx.x;       // 0..255
    const int lane = t & 63;
    const int wave = t >> 6;

    const float* xr = x + (size_t)row * NCLS;

    float acc  = 0.0f;   // partial output for dim = lane (this wave's share)
    float lsum = 0.0f;   // partial row sum (this thread's share)

    const int NV4 = NCLS / 4;                 // 2500 float4s per row
    const int NIT = (NV4 + 255) / 256;        // 10 block-iterations

    for (int it = 0; it < NIT; ++it) {
        const int i4 = it * 256 + t;
        float4 v = make_float4(0.f, 0.f, 0.f, 0.f);
        if (i4 < NV4) v = reinterpret_cast<const float4*>(xr)[i4];
        lsum += v.x + v.y + v.z + v.w;

        float comps[4] = {v.x, v.y, v.z, v.w};
        #pragma unroll
        for (int j = 0; j < 4; ++j) {
            unsigned long long m = __ballot(comps[j] != 0.0f);
            while (m) {
                const int l = __builtin_ctzll(m);
                m &= m - 1;
                const float val = __shfl(comps[j], l);   // j is unroll-const
                const int cls = (it * 256 + wave * 64 + l) * 4 + j;
                acc += val * emb[(size_t)cls * DIM + lane];
            }
        }
    }

    // wave-reduce lsum across 64 lanes
    #pragma unroll
    for (int off = 32; off > 0; off >>= 1) lsum += __shfl_xor(lsum, off);

    __shared__ float s_acc[4][DIM];
    __shared__ float s_sum[4];
    s_acc[wave][lane] = acc;
    if (lane == 0) s_sum[wave] = lsum;
    __syncthreads();

    if (wave == 0) {
        const float total = s_sum[0] + s_sum[1] + s_sum[2] + s_sum[3];
        const float a = s_acc[0][lane] + s_acc[1][lane] + s_acc[2][lane] + s_acc[3][lane];
        const float scale = 1.0f / fmaxf(total, 1.0f);
        out[(size_t)row * DIM + lane] = a * scale;
    }
}

extern "C" void kernel_launch(void* const* d_in, const int* in_sizes, int n_in,
                              void* d_out, int out_size, void* d_ws, size_t ws_size,
                              hipStream_t stream) {
    const float* x   = (const float*)d_in[0];   // [16,200,10000] f32
    const float* emb = (const float*)d_in[1];   // [10000,64] f32
    float* out = (float*)d_out;                 // [16,200,64] f32

    multihot_emb_kernel<<<NROWS, 256, 0, stream>>>(x, emb, out);
}

// Round 5
// 180.727 us; speedup vs baseline: 1.0520x; 1.0520x over previous
//
#include <hip/hip_runtime.h>

// MultiHotEmbedding: out[b,s,:] = (1/max(cnt,1)) * sum_{n: x[b,s,n]!=0} emb[n,:]
// B=16,S=200,N=10000,D=64. x is EXACTLY 0/1 by construction (bool->float),
// so count == sum(x) and the weighted sum is an unweighted sum of active rows.
//
// Two-phase per row (1 block = 256 thr = 4 waves per row):
//  P1: stream the 10000-float row as nontemporal float4 (no L2 pollution ->
//      emb table stays L2-resident), compact active class indices to LDS.
//  P2: 4 waves gather emb rows in parallel (lane = dim), counted loop so the
//      compiler can pipeline the loads. LDS reduce, scale, write 256B.

#define NCLS 10000
#define DIM 64
#define NROWS (16 * 200)
#define NV4 (NCLS / 4)          // 2500 float4 per row
#define MAXA 256                // mean actives=50, sigma~7; 256 is >25 sigma

typedef float f32x4 __attribute__((ext_vector_type(4)));

__global__ __launch_bounds__(256) void multihot_emb_kernel(
    const float* __restrict__ x,
    const float* __restrict__ emb,
    float* __restrict__ out) {

    const int row  = blockIdx.x;    // 0..3199
    const int t    = threadIdx.x;   // 0..255
    const int lane = t & 63;
    const int wave = t >> 6;

    __shared__ int   s_cls[MAXA];
    __shared__ int   s_cnt;
    __shared__ float s_acc[4][DIM];

    if (t == 0) s_cnt = 0;
    __syncthreads();

    const f32x4* xr = reinterpret_cast<const f32x4*>(x + (size_t)row * NCLS);

    // ---- phase 1: streaming scan + index compaction ----
    #pragma unroll
    for (int it = 0; it < (NV4 + 255) / 256; ++it) {
        const int i4 = it * 256 + t;
        if (i4 < NV4) {
            f32x4 v = __builtin_nontemporal_load(&xr[i4]);
            #pragma unroll
            for (int j = 0; j < 4; ++j) {
                if (v[j] != 0.0f) {
                    int p = atomicAdd(&s_cnt, 1);
                    if (p < MAXA) s_cls[p] = 4 * i4 + j;
                }
            }
        }
    }
    __syncthreads();

    int cnt = s_cnt;
    if (cnt > MAXA) cnt = MAXA;   // statistically unreachable

    // ---- phase 2: parallel gather, waves split the active list ----
    float acc = 0.0f;
    for (int k = wave; k < cnt; k += 4) {
        acc += emb[(size_t)s_cls[k] * DIM + lane];
    }

    s_acc[wave][lane] = acc;
    __syncthreads();

    if (wave == 0) {
        const float a = s_acc[0][lane] + s_acc[1][lane] +
                        s_acc[2][lane] + s_acc[3][lane];
        out[(size_t)row * DIM + lane] = a / fmaxf((float)cnt, 1.0f);
    }
}

extern "C" void kernel_launch(void* const* d_in, const int* in_sizes, int n_in,
                              void* d_out, int out_size, void* d_ws, size_t ws_size,
                              hipStream_t stream) {
    const float* x   = (const float*)d_in[0];   // [16,200,10000] f32
    const float* emb = (const float*)d_in[1];   // [10000,64] f32
    float* out = (float*)d_out;                 // [16,200,64] f32

    multihot_emb_kernel<<<NROWS, 256, 0, stream>>>(x, emb, out);
}